// Round 4
// baseline (551.116 us; speedup 1.0000x reference)
//
#include <hip/hip_runtime.h>
#include <math.h>

#define N_    64
#define T_    2000
#define ENC_  512
#define ATT_  256
#define SPK_  64
#define O_    80

__device__ __forceinline__ float sigmf_(float x) { return 1.0f / (1.0f + expf(-x)); }

// ---------------------------------------------------------------------------
// A1: attention logit partials.
// grid (aq=8, n=64), block 256 = 32 a-lanes x 8 t-groups.
// logitpart[(n*8+aq)*16 + t] = sum over this block's 32 a of tanh(e)*W_proj[a]
// ---------------------------------------------------------------------------
__global__ __launch_bounds__(256) void k_att_logits(
    const float* __restrict__ enc, const float* __restrict__ spkr,
    const float* __restrict__ speed, const float* __restrict__ W_enc,
    const float* __restrict__ b_enc, const float* __restrict__ W_spkr,
    const float* __restrict__ conv_prev, const float* __restrict__ W_speed_att,
    const float* __restrict__ W_proj, float* __restrict__ logitpart)
{
    const int aq  = blockIdx.x;
    const int n   = blockIdx.y;
    const int tid = threadIdx.x;
    const int al  = tid & 31;
    const int tg  = tid >> 5;
    const int a   = aq * 32 + al;

    __shared__ float encL[10 * 512];
    __shared__ float spkL[64];

    for (int f = tid; f < 10 * 512; f += 256) {
        int t = f >> 9, k = f & 511;
        encL[f] = enc[((size_t)n * T_ + t) * ENC_ + k];
    }
    if (tid < 64) spkL[tid] = spkr[n * 64 + tid];
    __syncthreads();

    // att_bias_spkr[a] = softsign(spkr . W_spkr[a])
    float bs;
    {
        const float* wr = W_spkr + a * 64;
        float b0 = 0.f, b1 = 0.f;
        #pragma unroll
        for (int s = 0; s < 64; s += 2) { b0 += spkL[s] * wr[s]; b1 += spkL[s + 1] * wr[s + 1]; }
        bs = b0 + b1;
    }
    bs = bs / (1.f + fabsf(bs));
    const float sa = speed[n] * W_speed_att[a];
    const float be = b_enc[a];
    const float wp = W_proj[a];

    const int t0 = tg;                 // t = tg, plus t = tg+8 for tg<2  -> covers t=0..9
    float a0a = 0.f, a0b = 0.f, a1a = 0.f, a1b = 0.f;
    const float* wrow = W_enc + (size_t)a * 512;
    const float* e0 = encL + t0 * 512;
    if (tg < 2) {
        const float* e1 = encL + (t0 + 8) * 512;
        #pragma unroll 4
        for (int k = 0; k < 512; k += 2) {
            float w0 = wrow[k], w1 = wrow[k + 1];
            a0a += w0 * e0[k]; a0b += w1 * e0[k + 1];
            a1a += w0 * e1[k]; a1b += w1 * e1[k + 1];
        }
    } else {
        #pragma unroll 8
        for (int k = 0; k < 512; k += 2) {
            a0a += wrow[k] * e0[k]; a0b += wrow[k + 1] * e0[k + 1];
        }
    }

    {   // finish t0
        float acc = a0a + a0b + be;
        float e = acc / (1.f + fabsf(acc));            // softsign(att_bias_enc)
        e += bs + sa + conv_prev[a * 31 + (15 - t0)];  // + spkr + speed + conv(one-hot)
        float v = tanhf(e) * wp;
        v += __shfl_xor(v, 1, 64);  v += __shfl_xor(v, 2, 64);
        v += __shfl_xor(v, 4, 64);  v += __shfl_xor(v, 8, 64);
        v += __shfl_xor(v, 16, 64);
        if (al == 0) logitpart[(n * 8 + aq) * 16 + t0] = v;
    }
    if (tg < 2) {   // finish t0+8
        int t1 = t0 + 8;
        float acc = a1a + a1b + be;
        float e = acc / (1.f + fabsf(acc));
        e += bs + sa + conv_prev[a * 31 + (15 - t1)];
        float v = tanhf(e) * wp;
        v += __shfl_xor(v, 1, 64);  v += __shfl_xor(v, 2, 64);
        v += __shfl_xor(v, 4, 64);  v += __shfl_xor(v, 8, 64);
        v += __shfl_xor(v, 16, 64);
        if (al == 0) logitpart[(n * 8 + aq) * 16 + t1] = v;
    }
}

// ---------------------------------------------------------------------------
// A2: per-batch: softmax over window, prenet, speed-proj, context.
// Writes context to d_out and assembles transposed LSTM input x0T[k][n]
// (k: 0..255 pre, 256..767 context, 768..831 spkr).
// grid 64 (n), block 256.
// ---------------------------------------------------------------------------
__global__ __launch_bounds__(256) void k_ctx_pre(
    const float* __restrict__ enc, const float* __restrict__ input_dec,
    const float* __restrict__ spkr, const int* __restrict__ lengths,
    const float* __restrict__ speed, const float* __restrict__ b_proj,
    const float* __restrict__ W_sp1, const float* __restrict__ b_sp1,
    const float* __restrict__ W_sp2, const float* __restrict__ b_sp2,
    const float* __restrict__ W_p1, const float* __restrict__ b_p1,
    const float* __restrict__ W_p2, const float* __restrict__ b_p2,
    const float* __restrict__ logitpart, float* __restrict__ x0T,
    float* __restrict__ ctx_out)
{
    const int n = blockIdx.x, tid = threadIdx.x;
    __shared__ float xL[144];
    __shared__ float hL[512];
    __shared__ float rL[256];
    __shared__ float spL[512];
    __shared__ float attL[10];

    if (tid < 80) xL[tid] = input_dec[n * 80 + tid];
    if (tid >= 80 && tid < 144) xL[tid] = spkr[n * 64 + (tid - 80)];
    if (tid >= 144 && tid < 208) x0T[(768 + tid - 144) * 64 + n] = spkr[n * 64 + (tid - 144)];
    { float rv = speed[n] * W_sp1[tid] + b_sp1[tid]; rL[tid] = rv > 0.f ? rv : 0.f; }
    __syncthreads();

    // prenet hidden (512 = 2/thread), K=144
    for (int j = tid; j < 512; j += 256) {
        const float* w = W_p1 + j * 144;
        float s0 = 0.f, s1 = 0.f;
        #pragma unroll 4
        for (int k = 0; k < 144; k += 2) { s0 += xL[k] * w[k]; s1 += xL[k + 1] * w[k + 1]; }
        float s = s0 + s1 + b_p1[j];
        hL[j] = s > 0.f ? s : 0.f;
    }
    __syncthreads();

    // prenet out (256 = 1/thread), K=512 -> x0T rows 0..255
    {
        const float* w = W_p2 + tid * 512;
        float s0 = 0.f, s1 = 0.f, s2 = 0.f, s3 = 0.f;
        #pragma unroll 4
        for (int k = 0; k < 512; k += 4) {
            s0 += hL[k] * w[k];     s1 += hL[k + 1] * w[k + 1];
            s2 += hL[k + 2] * w[k + 2]; s3 += hL[k + 3] * w[k + 3];
        }
        float s = s0 + s1 + s2 + s3 + b_p2[tid];
        x0T[tid * 64 + n] = s > 0.f ? s : 0.f;
    }

    // speed projection sp (512 = 2/thread), K=256
    for (int e = tid; e < 512; e += 256) {
        const float* w = W_sp2 + e * 256;
        float s0 = 0.f, s1 = 0.f, s2 = 0.f, s3 = 0.f;
        #pragma unroll 4
        for (int k = 0; k < 256; k += 4) {
            s0 += rL[k] * w[k];     s1 += rL[k + 1] * w[k + 1];
            s2 += rL[k + 2] * w[k + 2]; s3 += rL[k + 3] * w[k + 3];
        }
        spL[e] = tanhf(s0 + s1 + s2 + s3 + b_sp2[e]);
    }

    if (tid == 0) {  // softmax over the 10-wide window
        float l[10];
        for (int t = 0; t < 10; ++t) {
            float s = b_proj[0];
            for (int q = 0; q < 8; ++q) s += logitpart[(n * 8 + q) * 16 + t];
            l[t] = s;
        }
        int len = lengths[n];
        int len1 = (len > 1 ? len : 1) - 1;
        int hi = len1 < 9 ? len1 : 9;
        float m = -1e30f;
        for (int t = 0; t <= hi; ++t) m = fmaxf(m, l[t]);
        float S = 0.f;
        for (int t = 0; t < 10; ++t) {
            float w = (t <= hi) ? expf(l[t] - m) : 0.f;
            attL[t] = w; S += w;
        }
        S = fmaxf(S, 1e-12f);
        for (int t = 0; t < 10; ++t) attL[t] /= S;
    }
    __syncthreads();

    // context = sum_t att[t] * (enc[n,t,:] + sp)  -> d_out and x0T rows 256..767
    for (int e = tid; e < 512; e += 256) {
        const float* er = enc + (size_t)n * T_ * ENC_ + e;
        float spv = spL[e];
        float s = 0.f;
        #pragma unroll
        for (int t = 0; t < 10; ++t) s += attL[t] * (er[(size_t)t * ENC_] + spv);
        ctx_out[n * 512 + e] = s;
        x0T[(256 + e) * 64 + n] = s;
    }
}

// ---------------------------------------------------------------------------
// B: 3-gate (i,g,o — f-gate dead since c_prev=0) LSTM input GEMM, split-K=8.
// grid (rowtile=96, ks=8), block 256 = 4 waves x 8 rows/wave, lane = batch n.
// x staged in LDS as [k][64] (2-way bank alias = free).
// gp[ks][ur][n] partials; ur = gate*1024+col, gate in {i,g,o}.
// ---------------------------------------------------------------------------
template<int K, int KC>
__global__ __launch_bounds__(256) void k_gemm3(
    const float* __restrict__ W, const float* __restrict__ xT,
    float* __restrict__ gp)
{
    __shared__ float xL[KC * 64];
    const int rt = blockIdx.x;
    const int ks = blockIdx.y;
    const int tid = threadIdx.x;
    const int lane = tid & 63;
    const int w = __builtin_amdgcn_readfirstlane(tid >> 6);
    const int k0 = ks * KC;

    {
        const float4* src = (const float4*)(xT + (size_t)k0 * 64);
        float4* dst = (float4*)xL;
        for (int f = tid; f < KC * 16; f += 256) dst[f] = src[f];
    }
    __syncthreads();

    const int urb = rt * 32 + w * 8;
    float acc[8] = {0.f, 0.f, 0.f, 0.f, 0.f, 0.f, 0.f, 0.f};
    const float* wr[8];
    #pragma unroll
    for (int j = 0; j < 8; ++j) {
        int ur = urb + j;
        int row = ur + (ur < 1024 ? 0 : 1024);   // skip the f-gate block
        wr[j] = W + (size_t)row * K + k0;
    }
    #pragma unroll 4
    for (int kk = 0; kk < KC; ++kk) {
        float xv = xL[kk * 64 + lane];
        #pragma unroll
        for (int j = 0; j < 8; ++j) acc[j] += xv * wr[j][kk];
    }
    #pragma unroll
    for (int j = 0; j < 8; ++j)
        gp[(size_t)(ks * 3072 + urb + j) * 64 + lane] = acc[j];
}

// ---------------------------------------------------------------------------
// act: combine split-K partials + biases, apply LSTM cell (h_prev=c_prev=0).
// grid 256, block 256; one thread per (col,n); output transposed hT[col][n].
// ---------------------------------------------------------------------------
__global__ __launch_bounds__(256) void k_lstm_act(
    const float* __restrict__ gp, const float* __restrict__ bih,
    const float* __restrict__ bhh, float* __restrict__ hT)
{
    const int flat = blockIdx.x * 256 + threadIdx.x;   // < 65536
    const int nn = flat & 63, col = flat >> 6;
    float gi = bih[col] + bhh[col];
    float gg = bih[2048 + col] + bhh[2048 + col];
    float go = bih[3072 + col] + bhh[3072 + col];
    #pragma unroll
    for (int ks = 0; ks < 8; ++ks) {
        const float* base = gp + (size_t)ks * 3072 * 64;
        gi += base[(size_t)col * 64 + nn];
        gg += base[(size_t)(1024 + col) * 64 + nn];
        go += base[(size_t)(2048 + col) * 64 + nn];
    }
    float c = sigmf_(gi) * tanhf(gg);
    float h = sigmf_(go) * tanhf(c);
    hT[flat] = h;
}

// ---------------------------------------------------------------------------
// D: out_linear over [h2 | context], K=1536. grid 160 (one block per output
// column j), 4 waves k-split + LDS reduce, lane = n.
// ---------------------------------------------------------------------------
__global__ __launch_bounds__(256) void k_out(
    const float* __restrict__ h2T, const float* __restrict__ x0T,
    const float* __restrict__ W_out, const float* __restrict__ b_out,
    float* __restrict__ out)
{
    const int j = blockIdx.x;
    const int tid = threadIdx.x, lane = tid & 63;
    const int w = __builtin_amdgcn_readfirstlane(tid >> 6);
    __shared__ float red[4][64];

    const float* wrow = W_out + (size_t)j * 1536 + w * 384;
    float s0 = 0.f, s1 = 0.f;
    for (int k = 0; k < 384; k += 2) {
        int kg = w * 384 + k;
        const float* x0p = (kg < 1024) ? (h2T + (size_t)kg * 64)
                                       : (x0T + (size_t)(256 + kg - 1024) * 64);
        int kg1 = kg + 1;
        const float* x1p = (kg1 < 1024) ? (h2T + (size_t)kg1 * 64)
                                        : (x0T + (size_t)(256 + kg1 - 1024) * 64);
        s0 += x0p[lane] * wrow[k];
        s1 += x1p[lane] * wrow[k + 1];
    }
    red[w][lane] = s0 + s1;
    __syncthreads();
    if (w == 0) {
        float t = red[0][lane] + red[1][lane] + red[2][lane] + red[3][lane] + b_out[j];
        out[(size_t)lane * 160 + j] = t;
    }
}

// ---------------------------------------------------------------------------
extern "C" void kernel_launch(void* const* d_in, const int* in_sizes, int n_in,
                              void* d_out, int out_size, void* d_ws, size_t ws_size,
                              hipStream_t stream)
{
    (void)in_sizes; (void)n_in; (void)out_size; (void)ws_size;

    const float* input_enc   = (const float*)d_in[0];
    const float* input_dec   = (const float*)d_in[1];
    const float* spkr        = (const float*)d_in[2];
    const int*   lengths     = (const int*)  d_in[3];
    const float* speed       = (const float*)d_in[4];
    const float* W_enc       = (const float*)d_in[5];
    const float* b_enc       = (const float*)d_in[6];
    const float* W_spkr      = (const float*)d_in[7];
    const float* conv_prev   = (const float*)d_in[8];
    const float* W_speed_att = (const float*)d_in[9];
    const float* W_proj      = (const float*)d_in[10];
    const float* b_proj      = (const float*)d_in[11];
    const float* W_sp1       = (const float*)d_in[12];
    const float* b_sp1       = (const float*)d_in[13];
    const float* W_sp2       = (const float*)d_in[14];
    const float* b_sp2       = (const float*)d_in[15];
    const float* W_p1        = (const float*)d_in[16];
    const float* b_p1        = (const float*)d_in[17];
    const float* W_p2        = (const float*)d_in[18];
    const float* b_p2        = (const float*)d_in[19];
    const float* Wih0        = (const float*)d_in[20];
    /* Whh0 = d_in[21] unused: h_prev = 0 */
    const float* bih0        = (const float*)d_in[22];
    const float* bhh0        = (const float*)d_in[23];
    const float* Wih1        = (const float*)d_in[24];
    /* Whh1 = d_in[25] unused */
    const float* bih1        = (const float*)d_in[26];
    const float* bhh1        = (const float*)d_in[27];
    const float* W_out       = (const float*)d_in[28];
    const float* b_out       = (const float*)d_in[29];

    float* out = (float*)d_out;          // [0,10240) output, [10240,43008) context
    float* wsf = (float*)d_ws;
    float* logitpart = wsf;              //   8192 floats
    float* x0T = wsf + 8192;             //  53248 floats: [pre|ctx|spkr] transposed [832][64]
    float* x1T = wsf + 61440;            //  65536 floats: h1 transposed [1024][64]
    float* h2T = wsf + 126976;           //  65536 floats: h2 transposed
    float* gp  = wsf + 192512;           // 8*3072*64 floats (reused for both layers)

    k_att_logits<<<dim3(8, 64), 256, 0, stream>>>(
        input_enc, spkr, speed, W_enc, b_enc, W_spkr, conv_prev, W_speed_att,
        W_proj, logitpart);

    k_ctx_pre<<<dim3(64), 256, 0, stream>>>(
        input_enc, input_dec, spkr, lengths, speed, b_proj,
        W_sp1, b_sp1, W_sp2, b_sp2, W_p1, b_p1, W_p2, b_p2,
        logitpart, x0T, out + 10240);

    k_gemm3<832, 104><<<dim3(96, 8), 256, 0, stream>>>(Wih0, x0T, gp);
    k_lstm_act<<<dim3(256), 256, 0, stream>>>(gp, bih0, bhh0, x1T);

    k_gemm3<1024, 128><<<dim3(96, 8), 256, 0, stream>>>(Wih1, x1T, gp);
    k_lstm_act<<<dim3(256), 256, 0, stream>>>(gp, bih1, bhh1, h2T);

    k_out<<<dim3(160), 256, 0, stream>>>(h2T, x0T, W_out, b_out, out);
}